// Round 7
// baseline (228.594 us; speedup 1.0000x reference)
//
#include <hip/hip_runtime.h>
#include <math.h>

typedef _Float16 half_t;
typedef _Float16 half4 __attribute__((ext_vector_type(4)));
typedef _Float16 half8 __attribute__((ext_vector_type(8)));
typedef float f32x4 __attribute__((ext_vector_type(4)));

#define LOG2E 1.44269504088896f

// async global -> LDS, 16 B per lane; lds base wave-uniform, lane i at base+i*16.
__device__ __forceinline__ void gload16(const void* g, void* l) {
    __builtin_amdgcn_global_load_lds(
        (const __attribute__((address_space(1))) unsigned int*)g,
        (__attribute__((address_space(3))) unsigned int*)l, 16, 0, 0);
}

// ---------------------------------------------------------------------------
// prep: group-reduced effective weights (fp16) + log2-domain bias table (fp32).
// ---------------------------------------------------------------------------
__global__ void prep(const float* __restrict__ Wq, const float* __restrict__ Wk,
                     const float* __restrict__ Wv, const float* __restrict__ Wo,
                     const float* __restrict__ rb,
                     half_t* __restrict__ Wqkv, half_t* __restrict__ Wo_e,
                     float* __restrict__ btab) {
    int idx = blockIdx.x * 256 + threadIdx.x;
    if (idx < 768 * 1024) {
        int row = idx >> 10, col = idx & 1023;
        int sec = row >> 8;
        int r = row & 255;
        int h = r >> 6, d = r & 63;
        const float* W = (sec == 0) ? Wq : ((sec == 1) ? Wk : Wv);
        float s = 0.f;
        #pragma unroll
        for (int g = 0; g < 4; ++g) s += W[((g * 4 + h) * 64 + d) * 1024 + col];
        s *= (sec == 0) ? LOG2E : 0.25f;   // fold log2e into q-projection
        Wqkv[idx] = (half_t)s;
    }
    if (idx < 1024 * 256) {
        int m = idx >> 8, c = idx & 255;
        float s = 0.f;
        #pragma unroll
        for (int g = 0; g < 4; ++g) s += Wo[m * 1024 + g * 256 + c];
        Wo_e[idx] = (half_t)s;
    }
    if (idx < 4 * 4096) {
        int h = idx >> 12, dpos = idx & 4095;
        int delta = dpos - 2048;
        int bucket = (delta > 0) ? 16 : 0;
        int ad = delta < 0 ? -delta : delta;
        if (ad < 8) bucket += ad;
        else {
            int large = 8 + (int)(logf((float)ad * 0.125f) / logf(16.0f) * 8.0f);
            bucket += (large < 15) ? large : 15;
        }
        float s = 0.f;
        #pragma unroll
        for (int g = 0; g < 4; ++g) s += rb[bucket * 16 + g * 4 + h];
        btab[idx] = s * 0.25f * LOG2E;     // log2-domain bias
    }
}

// ---------------------------------------------------------------------------
// hs fp32 -> fp16
// ---------------------------------------------------------------------------
__global__ __launch_bounds__(256) void cvt_hs(const float* __restrict__ hs,
                                              half_t* __restrict__ hsh) {
    int i = (blockIdx.x * 256 + threadIdx.x) * 8;
    f32x4 a = *(const f32x4*)&hs[i];
    f32x4 b = *(const f32x4*)&hs[i + 4];
    half8 o;
    #pragma unroll
    for (int j = 0; j < 4; ++j) { o[j] = (half_t)a[j]; o[4 + j] = (half_t)b[j]; }
    *(half8*)&hsh[i] = o;
}

// ---------------------------------------------------------------------------
// MFMA NT GEMM: C[M,N] = A[M,K]*B[N,K]^T, fp16 in. 128x64 tile, 4 waves of
// 64x32, BK=64 (16 MFMA / 2 barriers), global_load_lds(16B), XOR-swizzled
// unpadded LDS (stride 64 halfs, 8-chunk swizzle).
// If vtp != null and this is a V column-block (colBase >= 512), the result is
// written TRANSPOSED to vt[(b*4+h)*64+d][n] instead of C (fuses transpose_v).
// ---------------------------------------------------------------------------
__global__ __launch_bounds__(256) void gemm_nt_mfma(const half_t* __restrict__ A,
                                                    const half_t* __restrict__ B,
                                                    void* __restrict__ Cptr,
                                                    int M, int N, int K, int store_half,
                                                    half_t* __restrict__ vtp) {
    __shared__ __attribute__((aligned(16))) half_t As[128 * 64];
    __shared__ __attribute__((aligned(16))) half_t Bs[64 * 64];
    int tid = threadIdx.x;
    int w = tid >> 6, lane = tid & 63;
    int c = lane & 15, quad = lane >> 4;
    int rowBase = blockIdx.y * 128, colBase = blockIdx.x * 64;
    int wr = (w & 1) * 64, wc = (w >> 1) * 32;

    f32x4 acc[4][2];
    #pragma unroll
    for (int i = 0; i < 4; ++i)
        #pragma unroll
        for (int j = 0; j < 2; ++j) acc[i][j] = (f32x4)(0.f);

    int srow = tid >> 3;                          // 0..31
    int kcs = ((tid & 7) ^ (srow & 7)) * 8;       // swizzled source k-chunk
    int rx = c & 7;

    for (int k0 = 0; k0 < K; k0 += 64) {
        __syncthreads();
        #pragma unroll
        for (int p = 0; p < 4; ++p)
            gload16(&A[(size_t)(rowBase + srow + 32 * p) * K + k0 + kcs],
                    &As[p * 2048 + w * 512]);
        #pragma unroll
        for (int p = 0; p < 2; ++p)
            gload16(&B[(size_t)(colBase + srow + 32 * p) * K + k0 + kcs],
                    &Bs[p * 2048 + w * 512]);
        __syncthreads();

        #pragma unroll
        for (int kh = 0; kh < 2; ++kh) {
            int xk = ((quad + 4 * kh) ^ rx) * 8;
            half8 af[4], bf[2];
            #pragma unroll
            for (int i = 0; i < 4; ++i)
                af[i] = *(const half8*)&As[(wr + i * 16 + c) * 64 + xk];
            #pragma unroll
            for (int j = 0; j < 2; ++j)
                bf[j] = *(const half8*)&Bs[(wc + j * 16 + c) * 64 + xk];
            #pragma unroll
            for (int i = 0; i < 4; ++i)
                #pragma unroll
                for (int j = 0; j < 2; ++j)
                    acc[i][j] = __builtin_amdgcn_mfma_f32_16x16x32_f16(af[i], bf[j], acc[i][j], 0, 0, 0);
        }
    }

    if (vtp && colBase >= 512) {
        // V block: write transposed only. h uniform per block.
        int h = (colBase - 512) >> 6;
        #pragma unroll
        for (int i = 0; i < 4; ++i)
            #pragma unroll
            for (int j = 0; j < 2; ++j) {
                int row0 = rowBase + wr + i * 16 + quad * 4;   // 4 consecutive tokens
                int dd = wc + j * 16 + c;
                int b = row0 >> 11, n = row0 & 2047;
                half4 pk;
                #pragma unroll
                for (int reg = 0; reg < 4; ++reg) pk[reg] = (half_t)acc[i][j][reg];
                *(half4*)&vtp[((size_t)((b * 4 + h) * 64 + dd)) * 2048 + n] = pk;
            }
        return;
    }

    #pragma unroll
    for (int i = 0; i < 4; ++i)
        #pragma unroll
        for (int j = 0; j < 2; ++j)
            #pragma unroll
            for (int reg = 0; reg < 4; ++reg) {
                size_t row = rowBase + wr + i * 16 + quad * 4 + reg;
                size_t col = colBase + wc + j * 16 + c;
                if (store_half) ((half_t*)Cptr)[row * N + col] = (half_t)acc[i][j][reg];
                else            ((float*)Cptr)[row * N + col] = acc[i][j][reg];
            }
}

// ---------------------------------------------------------------------------
// Split-K flash attention, S^T + O^T formulation.
// Block = (qtile 64, h, b, split s): keys [s*1024, +1024), 16 iters.
//  S^T = K Q^T (A=K from dbuf LDS, B=Q regs)  -> D[key, q=lane&15]
//  per-lane softmax (q fixed per lane): in-lane 16-key reduce + 2 swizzles
//  O^T = V^T P^T (A=V straight from GLOBAL vt - VMEM pipe, not LDS;
//                 B=P^T from wave-private swizzled LDS round-trip)
//  -> alpha is per-lane (no bpermute), epilogue b64 stores.
// One __syncthreads per iter (drains K prefetch vmcnt). LDS 28.6 KB.
// ---------------------------------------------------------------------------
__global__ __launch_bounds__(256) void attn(const half_t* __restrict__ qkv,
                                            const half_t* __restrict__ vt,
                                            const float* __restrict__ btab,
                                            half_t* __restrict__ Opart,
                                            float* __restrict__ ml) {
    __shared__ __attribute__((aligned(16))) half_t Ks[2][64 * 64];
    __shared__ __attribute__((aligned(16))) half_t Ps[4 * 16 * 64];
    __shared__ float bstat[1152];

    int tid = threadIdx.x;
    int w = tid >> 6, lane = tid & 63;
    int c = lane & 15, quad = lane >> 4;
    int qt = blockIdx.x, h = blockIdx.y;
    int b = blockIdx.z >> 1, s = blockIdx.z & 1;
    int q0 = qt * 64;
    int bh = b * 4 + h;
    int k0g = s * 1024;

    // Q fragments (B-operand: n=q=c, k=quad*8+j), q pre-scaled by log2e
    const half_t* qrow = qkv + (size_t)(b * 2048 + q0 + w * 16 + c) * 768 + h * 64;
    half8 qf0 = *(const half8*)(qrow + quad * 8);
    half8 qf1 = *(const half8*)(qrow + 32 + quad * 8);

    // far-field bias constants (bucket saturates for |delta|>=128)
    float cpos = btab[h * 4096 + 4095];
    float cneg = btab[h * 4096];

    // bias window: bstat[j] = btab[h][clamp(k0g - q0 - 63 + 2048 + j)]
    int bbase = k0g - q0 - 63 + 2048;
    for (int j = tid; j < 1152; j += 256) {
        int gi = bbase + j;
        gi = gi < 0 ? 0 : (gi > 4095 ? 4095 : gi);
        bstat[j] = btab[h * 4096 + gi];
    }

    // K staging: srow = tid>>3 (0..31, +32 on 2nd instr), chunk tid&7,
    // source chunk xor-swizzled by row&7.
    int srow = tid >> 3;
    int kcs = ((tid & 7) ^ (srow & 7)) * 8;
    const half_t* gK = qkv + (size_t)(b * 2048 + k0g + srow) * 768 + 256 + h * 64 + kcs;
    const half_t* gVbase = vt + (size_t)(bh * 64) * 2048 + k0g;

    // prologue: tile 0 -> buffer 0
    gload16(gK,                    &Ks[0][w * 512]);
    gload16(gK + (size_t)32 * 768, &Ks[0][2048 + w * 512]);
    __syncthreads();   // drains prologue K + bias staging

    f32x4 O[4];
    #pragma unroll
    for (int i = 0; i < 4; ++i) O[i] = (f32x4)(0.f);
    float mrow = -1e30f, lrow = 0.f;

    int rx = c & 7;
    half_t* pw = &Ps[w * 16 * 64];
    // P^T write geometry: b64 at q=c, keys kb*16+quad*4..+3 -> chunk swizzled
    int pq0 = (quad >> 1);      // chunk contribution of quad
    int pq1 = (quad & 1) * 4;   // in-chunk half offset

    for (int it = 0; it < 16; ++it) {
        int cur = it & 1;
        if (it + 1 < 16) {              // async K prefetch -> other buffer
            const half_t* gKn = gK + (size_t)((it + 1) * 64) * 768;
            gload16(gKn,                    &Ks[cur ^ 1][w * 512]);
            gload16(gKn + (size_t)32 * 768, &Ks[cur ^ 1][2048 + w * 512]);
        }
        int ktg = k0g + it * 64;
        const half_t* KsC = Ks[cur];

        // S^T = K Q^T : D[key = kb*16 + quad*4+rg, q = c]
        f32x4 ST[4];
        #pragma unroll
        for (int kb = 0; kb < 4; ++kb) {
            int row = kb * 16 + c;
            half8 kf0 = *(const half8*)&KsC[row * 64 + (quad ^ rx) * 8];
            half8 kf1 = *(const half8*)&KsC[row * 64 + ((quad + 4) ^ rx) * 8];
            f32x4 a = (f32x4)(0.f);
            a = __builtin_amdgcn_mfma_f32_16x16x32_f16(kf0, qf0, a, 0, 0, 0);
            a = __builtin_amdgcn_mfma_f32_16x16x32_f16(kf1, qf1, a, 0, 0, 0);
            ST[kb] = a;
        }

        // bias: constant fast path for far tiles, LDS path for near
        float cb;
        if (ktg >= q0 + 191) {
            cb = cpos;
        } else if (ktg + 191 <= q0) {
            cb = cneg;
        } else {
            cb = 0.f;
            int jb = it * 64 + 63 - (w * 16 + c);
            #pragma unroll
            for (int kb = 0; kb < 4; ++kb)
                #pragma unroll
                for (int rg = 0; rg < 4; ++rg)
                    ST[kb][rg] += bstat[jb + kb * 16 + quad * 4 + rg];
        }

        // row max: in-lane 16 keys -> cross-quad (2 swizzles)
        float tmax = -1e30f;
        #pragma unroll
        for (int kb = 0; kb < 4; ++kb)
            #pragma unroll
            for (int rg = 0; rg < 4; ++rg) tmax = fmaxf(tmax, ST[kb][rg]);
        tmax += cb;
        tmax = fmaxf(tmax, __shfl_xor(tmax, 16));
        tmax = fmaxf(tmax, __shfl_xor(tmax, 32));

        float mnew = fmaxf(mrow, tmax);
        float alpha = exp2f(mrow - mnew);
        mrow = mnew;
        float madj = mnew - cb;

        // p = exp2(S - madj); pack 4 keys -> swizzled b64 into wave-private Ps
        float lsum = 0.f;
        #pragma unroll
        for (int kb = 0; kb < 4; ++kb) {
            half4 pk;
            #pragma unroll
            for (int rg = 0; rg < 4; ++rg) {
                float p = exp2f(ST[kb][rg] - madj);
                lsum += p;
                pk[rg] = (half_t)p;
            }
            int swch = (kb * 2 + pq0) ^ rx;
            *(half4*)&pw[c * 64 + swch * 8 + pq1] = pk;
        }
        lsum += __shfl_xor(lsum, 16);
        lsum += __shfl_xor(lsum, 32);
        lrow = lrow * alpha + lsum;

        __asm__ __volatile__("s_waitcnt lgkmcnt(0)" ::: "memory");  // wave-private Ps

        // O^T[d, q] += V^T P^T : A = V^T straight from global (VMEM pipe),
        // B = P^T from Ps (n=q=c, k=key=quad*8+j, chunk-swizzled).
        half8 pf0 = *(const half8*)&pw[c * 64 + (quad ^ rx) * 8];
        half8 pf1 = *(const half8*)&pw[c * 64 + ((quad + 4) ^ rx) * 8];
        #pragma unroll
        for (int db = 0; db < 4; ++db) {
            const half_t* gV = gVbase + (size_t)(db * 16 + c) * 2048 + it * 64;
            half8 vf0 = *(const half8*)(gV + quad * 8);
            half8 vf1 = *(const half8*)(gV + 32 + quad * 8);
            f32x4 o = O[db];
            #pragma unroll
            for (int rg = 0; rg < 4; ++rg) o[rg] *= alpha;      // per-lane alpha!
            o = __builtin_amdgcn_mfma_f32_16x16x32_f16(vf0, pf0, o, 0, 0, 0);
            o = __builtin_amdgcn_mfma_f32_16x16x32_f16(vf1, pf1, o, 0, 0, 0);
            O[db] = o;
        }

        __syncthreads();   // all waves off cur; drains K prefetch (vmcnt 0)
    }

    // store unnormalized partial: O^T regs hold (d = db*16+quad*4+rg, q = c)
    int pb = (bh * 32 + qt) * 2 + s;
    #pragma unroll
    for (int db = 0; db < 4; ++db) {
        half4 pk;
        #pragma unroll
        for (int rg = 0; rg < 4; ++rg) pk[rg] = (half_t)O[db][rg];
        *(half4*)&Opart[((size_t)pb * 64 + w * 16 + c) * 64 + db * 16 + quad * 4] = pk;
    }
    if (quad == 0) {
        ml[pb * 128 + w * 16 + c] = mrow;
        ml[pb * 128 + 64 + w * 16 + c] = lrow;
    }
}

// ---------------------------------------------------------------------------
// merge the two split-K partials -> ab[b*2048+n][h*64+d]
// ---------------------------------------------------------------------------
__global__ __launch_bounds__(256) void merge(const half_t* __restrict__ Opart,
                                             const float* __restrict__ ml,
                                             half_t* __restrict__ ab) {
    int bq = blockIdx.x;            // bh*32 + qt
    int bh = bq >> 5, qt = bq & 31;
    int b = bh >> 2, h = bh & 3;
    int row = threadIdx.x >> 2;
    int cg = (threadIdx.x & 3) * 16;
    int p0 = bq * 2, p1 = p0 + 1;
    float m1 = ml[p0 * 128 + row], l1 = ml[p0 * 128 + 64 + row];
    float m2 = ml[p1 * 128 + row], l2 = ml[p1 * 128 + 64 + row];
    float m = fmaxf(m1, m2);
    float w1 = exp2f(m1 - m), w2 = exp2f(m2 - m);
    float inv = 1.f / (l1 * w1 + l2 * w2);
    const half8* o1 = (const half8*)&Opart[((size_t)p0 * 64 + row) * 64 + cg];
    const half8* o2 = (const half8*)&Opart[((size_t)p1 * 64 + row) * 64 + cg];
    half_t* dst = ab + (size_t)(b * 2048 + qt * 64 + row) * 256 + h * 64 + cg;
    #pragma unroll
    for (int v = 0; v < 2; ++v) {
        half8 x = o1[v], y = o2[v], o;
        #pragma unroll
        for (int j = 0; j < 8; ++j)
            o[j] = (half_t)(((float)x[j] * w1 + (float)y[j] * w2) * inv);
        *(half8*)(dst + v * 8) = o;
    }
}

// ---------------------------------------------------------------------------
// Launch. ws: Wqkv 1.5M | Wo_e .5M | btab 64K | hsh 16M | qkv 12M | vt 4M
// hsh region reused after QKV GEMM: Opart (8.4M) @0, ml (.5M) @8.4M, ab (4M) @9M
// ---------------------------------------------------------------------------
extern "C" void kernel_launch(void* const* d_in, const int* in_sizes, int n_in,
                              void* d_out, int out_size, void* d_ws, size_t ws_size,
                              hipStream_t stream) {
    (void)in_sizes; (void)n_in; (void)out_size; (void)ws_size;
    const float* hs = (const float*)d_in[0];
    const float* Wq = (const float*)d_in[1];
    const float* Wk = (const float*)d_in[2];
    const float* Wv = (const float*)d_in[3];
    const float* Wo = (const float*)d_in[4];
    const float* rb = (const float*)d_in[5];

    char* p = (char*)d_ws;
    half_t* Wqkv = (half_t*)p;            p += 768 * 1024 * 2;
    half_t* Wo_e = (half_t*)p;            p += 1024 * 256 * 2;
    float*  btab = (float*)p;             p += 4 * 4096 * 4;
    char*   hshp = p;                     p += (size_t)8192 * 1024 * 2;
    half_t* qkv  = (half_t*)p;            p += (size_t)8192 * 768 * 2;
    half_t* vt   = (half_t*)p;            p += (size_t)16 * 64 * 2048 * 2;
    half_t* hsh   = (half_t*)hshp;
    half_t* Opart = (half_t*)hshp;                               // 8.4 MB
    float*  mlbuf = (float*)(hshp + (size_t)1024 * 64 * 64 * 2); // 0.5 MB
    half_t* ab    = (half_t*)(hshp + (size_t)9 * 1024 * 1024);   // 4 MB
    float*  out  = (float*)d_out;

    prep<<<3072, 256, 0, stream>>>(Wq, Wk, Wv, Wo, rb, Wqkv, Wo_e, btab);
    cvt_hs<<<4096, 256, 0, stream>>>(hs, hsh);

    // qkv[8192,768] = hsh * Wqkv^T; V column-blocks go straight to vt (fused
    // transpose). 768 blocks = 3/CU.
    gemm_nt_mfma<<<dim3(12, 64), 256, 0, stream>>>(hsh, Wqkv, qkv, 8192, 768, 1024, 1, vt);

    // split-K=2 flash attention (1024 blocks, 4/CU)
    attn<<<dim3(32, 4, 8), 256, 0, stream>>>(qkv, vt, btab, Opart, mlbuf);
    merge<<<512, 256, 0, stream>>>(Opart, mlbuf, ab);

    // out[8192,1024] = ab[8192,256] * Wo_e[1024,256]^T  (1024 blocks, 4/CU)
    gemm_nt_mfma<<<dim3(16, 64), 256, 0, stream>>>(ab, Wo_e, out, 8192, 1024, 256, 0, nullptr);
}

// Round 9
// 182.368 us; speedup vs baseline: 1.2535x; 1.2535x over previous
//
#include <hip/hip_runtime.h>
#include <math.h>

typedef _Float16 half_t;
typedef _Float16 half4 __attribute__((ext_vector_type(4)));
typedef _Float16 half8 __attribute__((ext_vector_type(8)));
typedef float f32x4 __attribute__((ext_vector_type(4)));

#define LOG2E 1.44269504088896f

// async global -> LDS, 16 B per lane; lds base wave-uniform, lane i at base+i*16.
__device__ __forceinline__ void gload16(const void* g, void* l) {
    __builtin_amdgcn_global_load_lds(
        (const __attribute__((address_space(1))) unsigned int*)g,
        (__attribute__((address_space(3))) unsigned int*)l, 16, 0, 0);
}

// ---------------------------------------------------------------------------
// prep (fused): blocks 0..4095 convert hs fp32->fp16; blocks 4096.. build
// group-reduced effective weights (fp16) + log2-domain bias table (fp32).
// ---------------------------------------------------------------------------
__global__ __launch_bounds__(256) void prep(const float* __restrict__ hs,
                     const float* __restrict__ Wq, const float* __restrict__ Wk,
                     const float* __restrict__ Wv, const float* __restrict__ Wo,
                     const float* __restrict__ rb,
                     half_t* __restrict__ hsh,
                     half_t* __restrict__ Wqkv, half_t* __restrict__ Wo_e,
                     float* __restrict__ btab) {
    if (blockIdx.x < 4096) {
        int i = (blockIdx.x * 256 + threadIdx.x) * 8;
        f32x4 a = *(const f32x4*)&hs[i];
        f32x4 b = *(const f32x4*)&hs[i + 4];
        half8 o;
        #pragma unroll
        for (int j = 0; j < 4; ++j) { o[j] = (half_t)a[j]; o[4 + j] = (half_t)b[j]; }
        *(half8*)&hsh[i] = o;
        return;
    }
    int idx = (blockIdx.x - 4096) * 256 + threadIdx.x;
    if (idx < 768 * 1024) {
        int row = idx >> 10, col = idx & 1023;
        int sec = row >> 8;
        int r = row & 255;
        int h = r >> 6, d = r & 63;
        const float* W = (sec == 0) ? Wq : ((sec == 1) ? Wk : Wv);
        float s = 0.f;
        #pragma unroll
        for (int g = 0; g < 4; ++g) s += W[((g * 4 + h) * 64 + d) * 1024 + col];
        s *= (sec == 0) ? LOG2E : 0.25f;   // fold log2e into q-projection
        Wqkv[idx] = (half_t)s;
    }
    if (idx < 1024 * 256) {
        int m = idx >> 8, c = idx & 255;
        float s = 0.f;
        #pragma unroll
        for (int g = 0; g < 4; ++g) s += Wo[m * 1024 + g * 256 + c];
        Wo_e[idx] = (half_t)s;
    }
    if (idx < 4 * 4096) {
        int h = idx >> 12, dpos = idx & 4095;
        int delta = dpos - 2048;
        int bucket = (delta > 0) ? 16 : 0;
        int ad = delta < 0 ? -delta : delta;
        if (ad < 8) bucket += ad;
        else {
            int large = 8 + (int)(logf((float)ad * 0.125f) / logf(16.0f) * 8.0f);
            bucket += (large < 15) ? large : 15;
        }
        float s = 0.f;
        #pragma unroll
        for (int g = 0; g < 4; ++g) s += rb[bucket * 16 + g * 4 + h];
        btab[idx] = s * 0.25f * LOG2E;     // log2-domain bias
    }
}

// ---------------------------------------------------------------------------
// MFMA NT GEMM: C[M,N] = A[M,K]*B[N,K]^T, fp16 in. 128x64 tile, 4 waves of
// 64x32, BK=64 (16 MFMA / 2 barriers), global_load_lds(16B), XOR-swizzled
// unpadded LDS (stride 64 halfs, 8-chunk swizzle).
// If vtp != null and colBase >= 512 (a V column-block), the result is written
// TRANSPOSED to vt[(b*4+h)*64+d][n] (fuses transpose_v).
// ---------------------------------------------------------------------------
__global__ __launch_bounds__(256) void gemm_nt_mfma(const half_t* __restrict__ A,
                                                    const half_t* __restrict__ B,
                                                    void* __restrict__ Cptr,
                                                    int M, int N, int K, int store_half,
                                                    half_t* __restrict__ vtp) {
    __shared__ __attribute__((aligned(16))) half_t As[128 * 64];
    __shared__ __attribute__((aligned(16))) half_t Bs[64 * 64];
    int tid = threadIdx.x;
    int w = tid >> 6, lane = tid & 63;
    int c = lane & 15, quad = lane >> 4;
    int rowBase = blockIdx.y * 128, colBase = blockIdx.x * 64;
    int wr = (w & 1) * 64, wc = (w >> 1) * 32;

    f32x4 acc[4][2];
    #pragma unroll
    for (int i = 0; i < 4; ++i)
        #pragma unroll
        for (int j = 0; j < 2; ++j) acc[i][j] = (f32x4)(0.f);

    int srow = tid >> 3;                          // 0..31
    int kcs = ((tid & 7) ^ (srow & 7)) * 8;       // swizzled source k-chunk
    int rx = c & 7;

    for (int k0 = 0; k0 < K; k0 += 64) {
        __syncthreads();
        #pragma unroll
        for (int p = 0; p < 4; ++p)
            gload16(&A[(size_t)(rowBase + srow + 32 * p) * K + k0 + kcs],
                    &As[p * 2048 + w * 512]);
        #pragma unroll
        for (int p = 0; p < 2; ++p)
            gload16(&B[(size_t)(colBase + srow + 32 * p) * K + k0 + kcs],
                    &Bs[p * 2048 + w * 512]);
        __syncthreads();

        #pragma unroll
        for (int kh = 0; kh < 2; ++kh) {
            int xk = ((quad + 4 * kh) ^ rx) * 8;
            half8 af[4], bf[2];
            #pragma unroll
            for (int i = 0; i < 4; ++i)
                af[i] = *(const half8*)&As[(wr + i * 16 + c) * 64 + xk];
            #pragma unroll
            for (int j = 0; j < 2; ++j)
                bf[j] = *(const half8*)&Bs[(wc + j * 16 + c) * 64 + xk];
            #pragma unroll
            for (int i = 0; i < 4; ++i)
                #pragma unroll
                for (int j = 0; j < 2; ++j)
                    acc[i][j] = __builtin_amdgcn_mfma_f32_16x16x32_f16(af[i], bf[j], acc[i][j], 0, 0, 0);
        }
    }

    if (vtp && colBase >= 512) {
        int h = (colBase - 512) >> 6;
        #pragma unroll
        for (int i = 0; i < 4; ++i)
            #pragma unroll
            for (int j = 0; j < 2; ++j) {
                int row0 = rowBase + wr + i * 16 + quad * 4;   // 4 consecutive tokens
                int dd = wc + j * 16 + c;
                int b = row0 >> 11, n = row0 & 2047;
                half4 pk;
                #pragma unroll
                for (int reg = 0; reg < 4; ++reg) pk[reg] = (half_t)acc[i][j][reg];
                *(half4*)&vtp[((size_t)((b * 4 + h) * 64 + dd)) * 2048 + n] = pk;
            }
        return;
    }

    #pragma unroll
    for (int i = 0; i < 4; ++i)
        #pragma unroll
        for (int j = 0; j < 2; ++j)
            #pragma unroll
            for (int reg = 0; reg < 4; ++reg) {
                size_t row = rowBase + wr + i * 16 + quad * 4 + reg;
                size_t col = colBase + wc + j * 16 + c;
                if (store_half) ((half_t*)Cptr)[row * N + col] = (half_t)acc[i][j][reg];
                else            ((float*)Cptr)[row * N + col] = acc[i][j][reg];
            }
}

// ---------------------------------------------------------------------------
// Split-K flash attention, S^T + O^T, per-lane online softmax.
// q = lane&15 fixed per lane -> m/alpha are per-lane scalars (no bpermute);
// l accumulates in-lane under the shared running max (tmax reduced over the
// 4 quad-lanes via 2 swizzles); single cross-quad l-reduce at the end.
// Far tiles (|delta|>=128 everywhere): constant bias folded into madj.
// P stored fp16 AFTER max-shift (range-safe). Partials stored normalized
// (O/l) + (m,l) for the split merge.
//  S^T = K Q^T -> D[key, q=c];  O^T = V^T P^T -> D[d, q=c].
// ---------------------------------------------------------------------------
__global__ __launch_bounds__(256) void attn(const half_t* __restrict__ qkv,
                                            const half_t* __restrict__ vt,
                                            const float* __restrict__ btab,
                                            half_t* __restrict__ Opart,
                                            float* __restrict__ ml) {
    __shared__ __attribute__((aligned(16))) half_t Ks[64 * 64];
    __shared__ __attribute__((aligned(16))) half_t Vts[64 * 64];
    __shared__ __attribute__((aligned(16))) half_t Ps[4 * 16 * 72];
    __shared__ float bstat[1152];

    int tid = threadIdx.x;
    int w = tid >> 6, lane = tid & 63;
    int c = lane & 15, quad = lane >> 4;
    int qt = blockIdx.x, h = blockIdx.y;
    int b = blockIdx.z >> 1, s = blockIdx.z & 1;
    int q0 = qt * 64;
    int bh = b * 4 + h;
    int k0g = s * 1024;

    // Q fragments (B-operand: n=q=c, k=quad*8+j), pre-scaled by log2e
    const half_t* qrow = qkv + (size_t)(b * 2048 + q0 + w * 16 + c) * 768 + h * 64;
    half8 qf0 = *(const half8*)(qrow + quad * 8);
    half8 qf1 = *(const half8*)(qrow + 32 + quad * 8);

    // far-field bias constants (bucket saturates for |delta|>=128)
    float cpos = btab[h * 4096 + 4095];
    float cneg = btab[h * 4096];

    // bias window: bstat[j] = btab[h][clamp(k0g - q0 - 63 + 2048 + j)]
    int bbase = k0g - q0 - 63 + 2048;
    for (int j = tid; j < 1152; j += 256) {
        int gi = bbase + j;
        gi = gi < 0 ? 0 : (gi > 4095 ? 4095 : gi);
        bstat[j] = btab[h * 4096 + gi];
    }

    // staging: srow = tid>>3 (0..31, +32 on 2nd instr), chunk tid&7,
    // source chunk xor-swizzled by row&7.
    int srow = tid >> 3;
    int kcs = ((tid & 7) ^ (srow & 7)) * 8;
    const half_t* gK = qkv + (size_t)(b * 2048 + k0g + srow) * 768 + 256 + h * 64 + kcs;
    const half_t* gV = vt + (size_t)(bh * 64 + srow) * 2048 + k0g + kcs;

    f32x4 O[4];
    #pragma unroll
    for (int i = 0; i < 4; ++i) O[i] = (f32x4)(0.f);
    float mrow = -1e30f, lrow = 0.f;

    int rx = c & 7;
    half_t* pw = &Ps[w * 16 * 72];

    for (int it = 0; it < 16; ++it) {
        int ktg = k0g + it * 64;
        __syncthreads();                          // all waves done with LDS
        {
            const half_t* gKt = gK + (size_t)(it * 64) * 768;
            const half_t* gVt = gV + it * 64;
            gload16(gKt,                     &Ks[w * 512]);
            gload16(gKt + (size_t)32 * 768,  &Ks[2048 + w * 512]);
            gload16(gVt,                     &Vts[w * 512]);
            gload16(gVt + 32 * 2048,         &Vts[2048 + w * 512]);
        }
        __syncthreads();                          // vmcnt(0) drain

        // S^T = K Q^T : D[key = kb*16 + quad*4+rg, q = c]
        f32x4 ST[4];
        #pragma unroll
        for (int kb = 0; kb < 4; ++kb) {
            int row = kb * 16 + c;
            half8 kf0 = *(const half8*)&Ks[row * 64 + (quad ^ rx) * 8];
            half8 kf1 = *(const half8*)&Ks[row * 64 + ((quad + 4) ^ rx) * 8];
            f32x4 a = (f32x4)(0.f);
            a = __builtin_amdgcn_mfma_f32_16x16x32_f16(kf0, qf0, a, 0, 0, 0);
            a = __builtin_amdgcn_mfma_f32_16x16x32_f16(kf1, qf1, a, 0, 0, 0);
            ST[kb] = a;
        }

        // bias: near tiles add from LDS (cb=0); far tiles fold constant cb
        float cb;
        if (ktg >= q0 + 191) {
            cb = cpos;
        } else if (ktg + 191 <= q0) {
            cb = cneg;
        } else {
            cb = 0.f;
            int jb = it * 64 + 63 - (w * 16 + c);
            #pragma unroll
            for (int kb = 0; kb < 4; ++kb)
                #pragma unroll
                for (int rg = 0; rg < 4; ++rg)
                    ST[kb][rg] += bstat[jb + kb * 16 + quad * 4 + rg];
        }

        // tile max: in-lane 16 keys + 2 swizzles (lanes sharing q = c)
        float tmax = -1e30f;
        #pragma unroll
        for (int kb = 0; kb < 4; ++kb)
            #pragma unroll
            for (int rg = 0; rg < 4; ++rg) tmax = fmaxf(tmax, ST[kb][rg]);
        tmax += cb;
        tmax = fmaxf(tmax, __shfl_xor(tmax, 16));
        tmax = fmaxf(tmax, __shfl_xor(tmax, 32));

        float mnew = fmaxf(mrow, tmax);
        float alpha = exp2f(mrow - mnew);         // per-lane scalar
        mrow = mnew;
        float madj = mnew - cb;

        // p = exp2(S - madj) (max-shifted: fp16-safe); l in-lane; pack 4 keys
        float lsum = 0.f;
        #pragma unroll
        for (int kb = 0; kb < 4; ++kb) {
            half4 pk;
            #pragma unroll
            for (int rg = 0; rg < 4; ++rg) {
                float p = exp2f(ST[kb][rg] - madj);
                lsum += p;
                pk[rg] = (half_t)p;
            }
            *(half4*)&pw[c * 72 + kb * 16 + quad * 4] = pk;
        }
        lrow = lrow * alpha + lsum;               // in-lane (shared m)
        __asm__ __volatile__("s_waitcnt lgkmcnt(0)" ::: "memory");  // wave-private Ps

        // O^T[d, q=c] += V^T P^T : A = V^T (LDS), B = P^T (Ps row q=c)
        half8 pf0 = *(const half8*)&pw[c * 72 + quad * 8];
        half8 pf1 = *(const half8*)&pw[c * 72 + 32 + quad * 8];
        #pragma unroll
        for (int db = 0; db < 4; ++db) {
            int row = db * 16 + c;
            half8 vf0 = *(const half8*)&Vts[row * 64 + (quad ^ rx) * 8];
            half8 vf1 = *(const half8*)&Vts[row * 64 + ((quad + 4) ^ rx) * 8];
            f32x4 o = O[db];
            #pragma unroll
            for (int rg = 0; rg < 4; ++rg) o[rg] *= alpha;      // per-lane alpha
            o = __builtin_amdgcn_mfma_f32_16x16x32_f16(vf0, pf0, o, 0, 0, 0);
            o = __builtin_amdgcn_mfma_f32_16x16x32_f16(vf1, pf1, o, 0, 0, 0);
            O[db] = o;
        }
    }

    // total l across the 4 quad-lanes (same final m), normalize, store
    lrow += __shfl_xor(lrow, 16);
    lrow += __shfl_xor(lrow, 32);
    float inv = 1.0f / lrow;

    int pb = (bh * 32 + qt) * 2 + s;
    #pragma unroll
    for (int db = 0; db < 4; ++db) {
        half4 pk;
        #pragma unroll
        for (int rg = 0; rg < 4; ++rg) pk[rg] = (half_t)(O[db][rg] * inv);
        *(half4*)&Opart[((size_t)pb * 64 + w * 16 + c) * 64 + db * 16 + quad * 4] = pk;
    }
    if (quad == 0) {
        ml[pb * 128 + w * 16 + c] = mrow;
        ml[pb * 128 + 64 + w * 16 + c] = lrow;
    }
}

// ---------------------------------------------------------------------------
// merge the two split-K partials -> ab[b*2048+n][h*64+d]
// Partials normalized: out = (w1*O1 + w2*O2), w_i = 2^(m_i-m) * l_i / Z.
// ---------------------------------------------------------------------------
__global__ __launch_bounds__(256) void merge(const half_t* __restrict__ Opart,
                                             const float* __restrict__ ml,
                                             half_t* __restrict__ ab) {
    int bq = blockIdx.x;            // bh*32 + qt
    int bh = bq >> 5, qt = bq & 31;
    int b = bh >> 2, h = bh & 3;
    int row = threadIdx.x >> 2;
    int cg = (threadIdx.x & 3) * 16;
    int p0 = bq * 2, p1 = p0 + 1;
    float m1 = ml[p0 * 128 + row], l1 = ml[p0 * 128 + 64 + row];
    float m2 = ml[p1 * 128 + row], l2 = ml[p1 * 128 + 64 + row];
    float m = fmaxf(m1, m2);
    float a1 = exp2f(m1 - m) * l1, a2 = exp2f(m2 - m) * l2;
    float inv = 1.f / (a1 + a2);
    float w1 = a1 * inv, w2 = a2 * inv;
    const half8* o1 = (const half8*)&Opart[((size_t)p0 * 64 + row) * 64 + cg];
    const half8* o2 = (const half8*)&Opart[((size_t)p1 * 64 + row) * 64 + cg];
    half_t* dst = ab + (size_t)(b * 2048 + qt * 64 + row) * 256 + h * 64 + cg;
    #pragma unroll
    for (int v = 0; v < 2; ++v) {
        half8 x = o1[v], y = o2[v], o;
        #pragma unroll
        for (int j = 0; j < 8; ++j)
            o[j] = (half_t)((float)x[j] * w1 + (float)y[j] * w2);
        *(half8*)(dst + v * 8) = o;
    }
}

// ---------------------------------------------------------------------------
// Launch. ws: Wqkv 1.5M | Wo_e .5M | btab 64K | hsh 16M | qkv 12M | vt 4M
// hsh region reused after QKV GEMM: Opart (8.4M) @0, ml (.5M) @8.4M, ab (4M) @9M
// ---------------------------------------------------------------------------
extern "C" void kernel_launch(void* const* d_in, const int* in_sizes, int n_in,
                              void* d_out, int out_size, void* d_ws, size_t ws_size,
                              hipStream_t stream) {
    (void)in_sizes; (void)n_in; (void)out_size; (void)ws_size;
    const float* hs = (const float*)d_in[0];
    const float* Wq = (const float*)d_in[1];
    const float* Wk = (const float*)d_in[2];
    const float* Wv = (const float*)d_in[3];
    const float* Wo = (const float*)d_in[4];
    const float* rb = (const float*)d_in[5];

    char* p = (char*)d_ws;
    half_t* Wqkv = (half_t*)p;            p += 768 * 1024 * 2;
    half_t* Wo_e = (half_t*)p;            p += 1024 * 256 * 2;
    float*  btab = (float*)p;             p += 4 * 4096 * 4;
    char*   hshp = p;                     p += (size_t)8192 * 1024 * 2;
    half_t* qkv  = (half_t*)p;            p += (size_t)8192 * 768 * 2;
    half_t* vt   = (half_t*)p;            p += (size_t)16 * 64 * 2048 * 2;
    half_t* hsh   = (half_t*)hshp;
    half_t* Opart = (half_t*)hshp;                               // 8.4 MB
    float*  mlbuf = (float*)(hshp + (size_t)1024 * 64 * 64 * 2); // 0.5 MB
    half_t* ab    = (half_t*)(hshp + (size_t)9 * 1024 * 1024);   // 4 MB
    float*  out  = (float*)d_out;

    // fused cvt (blocks 0..4095) + weight/bias prep (blocks 4096..7167)
    prep<<<7168, 256, 0, stream>>>(hs, Wq, Wk, Wv, Wo, rb, hsh, Wqkv, Wo_e, btab);

    // qkv[8192,768] = hsh * Wqkv^T; V column-blocks go straight to vt (fused
    // transpose). 768 blocks = 3/CU.
    gemm_nt_mfma<<<dim3(12, 64), 256, 0, stream>>>(hsh, Wqkv, qkv, 8192, 768, 1024, 1, vt);

    // split-K=2 flash attention (1024 blocks, 4/CU)
    attn<<<dim3(32, 4, 8), 256, 0, stream>>>(qkv, vt, btab, Opart, mlbuf);
    merge<<<512, 256, 0, stream>>>(Opart, mlbuf, ab);

    // out[8192,1024] = ab[8192,256] * Wo_e[1024,256]^T  (1024 blocks, 4/CU)
    gemm_nt_mfma<<<dim3(16, 64), 256, 0, stream>>>(ab, Wo_e, out, 8192, 1024, 256, 0, nullptr);
}